// Round 3
// baseline (152.783 us; speedup 1.0000x reference)
//
#include <hip/hip_runtime.h>

#define BATCH 4096
#define NN 62
#define FF 5
#define KC 4          // K+1 Chebyshev terms
#define CO 64
#define NSEL 31
#define NF (NN*FF)    // 310
#define ADJ_S 68      // padded adj/u row stride (float4-aligned, bank-rotating)
#define XS_S 24       // padded xs row stride (20 used, 16B-aligned rows)
#define NTHREADS 320  // 5 waves
#define NB 2          // batches per block

__global__ __launch_bounds__(NTHREADS, 4) void gnn_fused(
    const float* __restrict__ x, const float* __restrict__ adj,
    const int* __restrict__ mask_idx,
    const float* __restrict__ gc_w, const float* __restrict__ gc_b,
    const float* __restrict__ gc1_w, const float* __restrict__ gc1_b,
    const float* __restrict__ gc2_w, const float* __restrict__ gc2_b,
    const float* __restrict__ fc1_w, const float* __restrict__ fc1_b,
    const float* __restrict__ fc2_w, const float* __restrict__ fc2_b,
    const float* __restrict__ cls_w, const float* __restrict__ cls_b,
    float* __restrict__ out)
{
    __shared__ __align__(16) float s_adj[NN*ADJ_S];        // 16864 B
    __shared__ __align__(16) float s_xs1[NB][NN*XS_S];     // 2*5952 B
    __shared__ __align__(16) float s_xs2[NB][NN*XS_S];     // 2*5952 B
    __shared__ __align__(16) float s_u1[NB][FF*ADJ_S];     // 2*1360 B
    __shared__ __align__(16) float s_u2[NB][FF*ADJ_S];     // 2*1360 B
    __shared__ __align__(16) float s_m[NB][64];
    __shared__ float s_dis1[64];
    __shared__ float s_dis2[NB][64];
    __shared__ float s_red[5][16];

    const int b0 = blockIdx.x * NB;
    const int t = threadIdx.x;
    const int w = t >> 6, lane = t & 63;

    // ---- stage: adj rows (coalesced, one row per wave-step), pads, x ----
    for (int r = w; r < NN; r += 5) {
        float v = (lane < NN) ? adj[r*NN + lane] : 0.0f;
        s_adj[r*ADJ_S + lane] = v;                  // covers cols 0..63
    }
    for (int i = t; i < NN*4; i += NTHREADS) {      // pad cols 64..67
        int r = i >> 2, c = 64 + (i & 3);
        s_adj[r*ADJ_S + c] = 0.0f;
    }
    // zero u-column pads once (cols 62..67 never rewritten; avoid NaN*0)
    for (int i = t; i < NB*FF*6; i += NTHREADS) {
        int bb = i / (FF*6), rem = i - bb*FF*6;
        int f = rem / 6, c = NN + (rem - f*6);
        s_u1[bb][f*ADJ_S + c] = 0.0f;
        s_u2[bb][f*ADJ_S + c] = 0.0f;
    }
    for (int i = t; i < NB*NF; i += NTHREADS) {
        int bb = (i >= NF) ? 1 : 0;
        int ii = i - bb*NF;
        int n = ii / FF, f = ii - n*FF;
        s_xs1[bb][n*XS_S + f] = x[(b0+bb)*NF + ii];
    }
    if (t < 64)       s_m[0][t]    = 0.0f;
    else if (t < 128) s_m[1][t-64] = 0.0f;
    __syncthreads();
    if (w < NB && lane < NSEL)
        s_m[w][mask_idx[(b0+w)*NSEL + lane]] = 1.0f;   // same-value races benign
    __syncthreads();

    // ---- degrees (waves 0/1 in parallel) + xs2 init ----
    if (w == 0 && lane < NN) {
        const float4* ar = (const float4*)&s_adj[lane*ADJ_S];
        const float4* mr = (const float4*)&s_m[0][0];
        float4 d1v = make_float4(0,0,0,0), d2v = make_float4(0,0,0,0);
        #pragma unroll
        for (int j4 = 0; j4 < 16; ++j4) {
            float4 a = ar[j4], m4 = mr[j4];
            d1v.x += a.x;      d1v.y += a.y;      d1v.z += a.z;      d1v.w += a.w;
            d2v.x += a.x*m4.x; d2v.y += a.y*m4.y; d2v.z += a.z*m4.z; d2v.w += a.w*m4.w;
        }
        float d1 = d1v.x + d1v.y + d1v.z + d1v.w;
        float d2 = (d2v.x + d2v.y + d2v.z + d2v.w) * s_m[0][lane];
        s_dis1[lane]    = (d1 > 0.f) ? rsqrtf(d1) : 0.f;
        s_dis2[0][lane] = (d2 > 0.f) ? rsqrtf(d2) : 0.f;
    }
    if (w == 1 && lane < NN) {
        const float4* ar = (const float4*)&s_adj[lane*ADJ_S];
        const float4* mr = (const float4*)&s_m[1][0];
        float4 d2v = make_float4(0,0,0,0);
        #pragma unroll
        for (int j4 = 0; j4 < 16; ++j4) {
            float4 a = ar[j4], m4 = mr[j4];
            d2v.x += a.x*m4.x; d2v.y += a.y*m4.y; d2v.z += a.z*m4.z; d2v.w += a.w*m4.w;
        }
        float d2 = (d2v.x + d2v.y + d2v.z + d2v.w) * s_m[1][lane];
        s_dis2[1][lane] = (d2 > 0.f) ? rsqrtf(d2) : 0.f;
    }
    for (int i = t; i < NB*NF; i += NTHREADS) {
        int bb = (i >= NF) ? 1 : 0;
        int ii = i - bb*NF;
        int n = ii / FF, f = ii - n*FF;
        s_xs2[bb][n*XS_S + f] = s_xs1[bb][n*XS_S + f] * s_m[bb][n];
    }
    __syncthreads();

    // ---- Chebyshev recursion: 2 paths x 2 batches per dot pass ----
    const int n_id = t / FF, f_id = t - n_id*FF;   // valid when t < NF
    for (int k = 1; k < KC; ++k) {
        if (t < NF) {
            int xo = n_id*XS_S + (k-1)*FF + f_id;
            int uo = f_id*ADJ_S + n_id;
            float d1 = s_dis1[n_id];
            s_u1[0][uo] = d1 * s_xs1[0][xo];
            s_u1[1][uo] = d1 * s_xs1[1][xo];
            s_u2[0][uo] = s_dis2[0][n_id] * s_xs2[0][xo];
            s_u2[1][uo] = s_dis2[1][n_id] * s_xs2[1][xo];
        }
        __syncthreads();
        if (t < NF) {
            const float4* ar  = (const float4*)&s_adj[n_id*ADJ_S];
            const float4* u10 = (const float4*)&s_u1[0][f_id*ADJ_S];
            const float4* u11 = (const float4*)&s_u1[1][f_id*ADJ_S];
            const float4* u20 = (const float4*)&s_u2[0][f_id*ADJ_S];
            const float4* u21 = (const float4*)&s_u2[1][f_id*ADJ_S];
            float4 a10 = make_float4(0,0,0,0), a11 = make_float4(0,0,0,0);
            float4 a20 = make_float4(0,0,0,0), a21 = make_float4(0,0,0,0);
            #pragma unroll
            for (int j4 = 0; j4 < 16; ++j4) {
                float4 av = ar[j4];
                float4 v10 = u10[j4], v11 = u11[j4], v20 = u20[j4], v21 = u21[j4];
                a10.x += av.x*v10.x; a10.y += av.y*v10.y; a10.z += av.z*v10.z; a10.w += av.w*v10.w;
                a11.x += av.x*v11.x; a11.y += av.y*v11.y; a11.z += av.z*v11.z; a11.w += av.w*v11.w;
                a20.x += av.x*v20.x; a20.y += av.y*v20.y; a20.z += av.z*v20.z; a20.w += av.w*v20.w;
                a21.x += av.x*v21.x; a21.y += av.y*v21.y; a21.z += av.z*v21.z; a21.w += av.w*v21.w;
            }
            float s10 = a10.x+a10.y+a10.z+a10.w, s11 = a11.x+a11.y+a11.z+a11.w;
            float s20 = a20.x+a20.y+a20.z+a20.w, s21 = a21.x+a21.y+a21.z+a21.w;
            float c = (k == 1) ? 1.0f : 2.0f;
            float v10s = -c * s_dis1[n_id] * s10;
            float v11s = -c * s_dis1[n_id] * s11;
            float v20s = -c * s_dis2[0][n_id] * s20;
            float v21s = -c * s_dis2[1][n_id] * s21;
            int xo = n_id*XS_S + k*FF + f_id;
            if (k >= 2) {
                int xp = n_id*XS_S + (k-2)*FF + f_id;
                v10s -= s_xs1[0][xp]; v11s -= s_xs1[1][xp];
                v20s -= s_xs2[0][xp]; v21s -= s_xs2[1][xp];
            }
            s_xs1[0][xo] = v10s; s_xs1[1][xo] = v11s;
            s_xs2[0][xo] = v20s; s_xs2[1][xo] = v21s;
        }
        __syncthreads();
    }

    // ---- einsum + ReLU + FC, one head per pass, both batches fused ----
    const int o = lane;   // CO == 64

    auto head_pass = [&](const float* __restrict__ wsrc, const float* __restrict__ bsrc,
                         const float* __restrict__ fsrc, const float (*xs)[NN*XS_S],
                         int nouts, int slot) {
        float4 wr[5];
        #pragma unroll
        for (int c = 0; c < 5; ++c)
            wr[c] = make_float4(wsrc[(4*c+0)*CO + o], wsrc[(4*c+1)*CO + o],
                                wsrc[(4*c+2)*CO + o], wsrc[(4*c+3)*CO + o]);
        float bias = bsrc[o];
        float a0[2] = {0,0}, a1[2] = {0,0}, a2[2] = {0,0};
        for (int n = w; n < NN; n += 5) {
            const float4* xr0 = (const float4*)&xs[0][n*XS_S];
            const float4* xr1 = (const float4*)&xs[1][n*XS_S];
            float4 h0v = make_float4(0,0,0,0), h1v = make_float4(0,0,0,0);
            #pragma unroll
            for (int c = 0; c < 5; ++c) {
                float4 x0v = xr0[c], x1v = xr1[c];
                h0v.x += x0v.x*wr[c].x; h0v.y += x0v.y*wr[c].y;
                h0v.z += x0v.z*wr[c].z; h0v.w += x0v.w*wr[c].w;
                h1v.x += x1v.x*wr[c].x; h1v.y += x1v.y*wr[c].y;
                h1v.z += x1v.z*wr[c].z; h1v.w += x1v.w*wr[c].w;
            }
            float h0 = fmaxf(bias + h0v.x + h0v.y + h0v.z + h0v.w, 0.f);
            float h1 = fmaxf(bias + h1v.x + h1v.y + h1v.z + h1v.w, 0.f);
            const float* fp = fsrc + (n*CO + o)*nouts;
            float f0 = fp[0], f1 = fp[1];
            a0[0] += h0*f0; a1[0] += h0*f1;
            a0[1] += h1*f0; a1[1] += h1*f1;
            if (nouts == 3) {
                float f2 = fp[2];
                a2[0] += h0*f2; a2[1] += h1*f2;
            }
        }
        #pragma unroll
        for (int off = 32; off > 0; off >>= 1) {
            #pragma unroll
            for (int bb = 0; bb < 2; ++bb) {
                a0[bb] += __shfl_down(a0[bb], off);
                a1[bb] += __shfl_down(a1[bb], off);
                if (nouts == 3) a2[bb] += __shfl_down(a2[bb], off);
            }
        }
        if (o == 0) {
            #pragma unroll
            for (int bb = 0; bb < 2; ++bb) {
                s_red[w][bb*8 + slot+0] = a0[bb];
                s_red[w][bb*8 + slot+1] = a1[bb];
                if (nouts == 3) s_red[w][bb*8 + slot+2] = a2[bb];
            }
        }
    };

    head_pass(gc1_w, gc1_b, fc1_w, s_xs1, 3, 0);
    head_pass(gc2_w, gc2_b, fc2_w, s_xs2, 3, 3);
    head_pass(gc_w,  gc_b,  cls_w, s_xs1, 2, 6);
    __syncthreads();

    // ---- epilogue: waves 0/1 each finish one batch ----
    if (w < NB && lane == 0) {
        const int bb = w;
        float r[8];
        #pragma unroll
        for (int i = 0; i < 8; ++i) {
            float s = 0.f;
            for (int wv = 0; wv < 5; ++wv) s += s_red[wv][bb*8 + i];
            r[i] = s;
        }
        float l1c[3], l2c[3];
        #pragma unroll
        for (int c = 0; c < 3; ++c) { l1c[c] = r[c] + fc1_b[c]; l2c[c] = r[3+c] + fc2_b[c]; }
        float g0 = r[6] + cls_b[0], g1 = r[7] + cls_b[1];
        float mx = fmaxf(g0, g1);
        float e0 = expf(g0 - mx), e1 = expf(g1 - mx);
        float inv = 1.0f / (e0 + e1);
        float p0 = e0*inv, p1 = e1*inv;
        float* op = out + (b0 + bb)*3;
        op[0] = l1c[0]*p0 + l2c[0]*p1;
        op[1] = l1c[1]*p0 + l2c[1]*p1;
        op[2] = l1c[2]*p0 + l2c[2]*p1;
    }
}

extern "C" void kernel_launch(void* const* d_in, const int* in_sizes, int n_in,
                              void* d_out, int out_size, void* d_ws, size_t ws_size,
                              hipStream_t stream) {
    const float* x      = (const float*)d_in[0];
    const float* adj    = (const float*)d_in[1];
    const int*   midx   = (const int*)  d_in[2];
    const float* gc_w   = (const float*)d_in[3];
    const float* gc_b   = (const float*)d_in[4];
    const float* gc1_w  = (const float*)d_in[5];
    const float* gc1_b  = (const float*)d_in[6];
    const float* gc2_w  = (const float*)d_in[7];
    const float* gc2_b  = (const float*)d_in[8];
    const float* fc1_w  = (const float*)d_in[9];
    const float* fc1_b  = (const float*)d_in[10];
    const float* fc2_w  = (const float*)d_in[11];
    const float* fc2_b  = (const float*)d_in[12];
    const float* cls_w  = (const float*)d_in[13];
    const float* cls_b  = (const float*)d_in[14];
    float* o = (float*)d_out;
    hipLaunchKernelGGL(gnn_fused, dim3(BATCH/NB), dim3(NTHREADS), 0, stream,
        x, adj, midx, gc_w, gc_b, gc1_w, gc1_b, gc2_w, gc2_b,
        fc1_w, fc1_b, fc2_w, fc2_b, cls_w, cls_b, o);
}

// Round 4
// 129.246 us; speedup vs baseline: 1.1821x; 1.1821x over previous
//
#include <hip/hip_runtime.h>

#define BATCH 4096
#define NN 62
#define FF 5
#define KC 4          // K+1 Chebyshev terms
#define CO 64
#define NSEL 31
#define NF (NN*FF)    // 310
#define ADJ_S 68      // padded adj/u row stride (float4-aligned, bank-rotating)
#define XS_S 24       // padded xs row stride (20 used, 16B-aligned rows)
#define NTHREADS 320  // 5 waves
#define NB 2          // batches per block

// NOTE: no min-waves floor — a floor forced the 64-VGPR quantum and spilled
// ~226 B/thread to scratch (R3: WRITE_SIZE 148 MB, dur 153us). LDS (47 KB)
// caps residency at 3 blocks/CU anyway, so VGPRs up to 128 are free.
__global__ __launch_bounds__(NTHREADS) void gnn_fused(
    const float* __restrict__ x, const float* __restrict__ adj,
    const int* __restrict__ mask_idx,
    const float* __restrict__ gc_w, const float* __restrict__ gc_b,
    const float* __restrict__ gc1_w, const float* __restrict__ gc1_b,
    const float* __restrict__ gc2_w, const float* __restrict__ gc2_b,
    const float* __restrict__ fc1_w, const float* __restrict__ fc1_b,
    const float* __restrict__ fc2_w, const float* __restrict__ fc2_b,
    const float* __restrict__ cls_w, const float* __restrict__ cls_b,
    float* __restrict__ out)
{
    __shared__ __align__(16) float s_adj[NN*ADJ_S];        // 16864 B
    __shared__ __align__(16) float s_xs1[NB][NN*XS_S];     // 2*5952 B
    __shared__ __align__(16) float s_xs2[NB][NN*XS_S];     // 2*5952 B
    __shared__ __align__(16) float s_u1[NB][FF*ADJ_S];     // 2*1360 B
    __shared__ __align__(16) float s_u2[NB][FF*ADJ_S];     // 2*1360 B
    __shared__ __align__(16) float s_m[NB][64];
    __shared__ float s_dis1[64];
    __shared__ float s_dis2[NB][64];
    __shared__ float s_red[5][16];

    const int b0 = blockIdx.x * NB;
    const int t = threadIdx.x;
    const int w = t >> 6, lane = t & 63;

    // ---- stage: adj rows (coalesced, one row per wave-step), pads, x ----
    for (int r = w; r < NN; r += 5) {
        float v = (lane < NN) ? adj[r*NN + lane] : 0.0f;
        s_adj[r*ADJ_S + lane] = v;                  // covers cols 0..63
    }
    for (int i = t; i < NN*4; i += NTHREADS) {      // pad cols 64..67
        int r = i >> 2, c = 64 + (i & 3);
        s_adj[r*ADJ_S + c] = 0.0f;
    }
    // zero u-column pads once (cols 62..67 never rewritten; avoid NaN*0)
    for (int i = t; i < NB*FF*6; i += NTHREADS) {
        int bb = i / (FF*6), rem = i - bb*FF*6;
        int f = rem / 6, c = NN + (rem - f*6);
        s_u1[bb][f*ADJ_S + c] = 0.0f;
        s_u2[bb][f*ADJ_S + c] = 0.0f;
    }
    for (int i = t; i < NB*NF; i += NTHREADS) {
        int bb = (i >= NF) ? 1 : 0;
        int ii = i - bb*NF;
        int n = ii / FF, f = ii - n*FF;
        s_xs1[bb][n*XS_S + f] = x[(b0+bb)*NF + ii];
    }
    if (t < 64)       s_m[0][t]    = 0.0f;
    else if (t < 128) s_m[1][t-64] = 0.0f;
    __syncthreads();
    if (w < NB && lane < NSEL)
        s_m[w][mask_idx[(b0+w)*NSEL + lane]] = 1.0f;   // same-value races benign
    __syncthreads();

    // ---- degrees (waves 0/1 in parallel) + xs2 init ----
    if (w == 0 && lane < NN) {
        const float4* ar = (const float4*)&s_adj[lane*ADJ_S];
        const float4* mr = (const float4*)&s_m[0][0];
        float4 d1v = make_float4(0,0,0,0), d2v = make_float4(0,0,0,0);
        #pragma unroll
        for (int j4 = 0; j4 < 16; ++j4) {
            float4 a = ar[j4], m4 = mr[j4];
            d1v.x += a.x;      d1v.y += a.y;      d1v.z += a.z;      d1v.w += a.w;
            d2v.x += a.x*m4.x; d2v.y += a.y*m4.y; d2v.z += a.z*m4.z; d2v.w += a.w*m4.w;
        }
        float d1 = d1v.x + d1v.y + d1v.z + d1v.w;
        float d2 = (d2v.x + d2v.y + d2v.z + d2v.w) * s_m[0][lane];
        s_dis1[lane]    = (d1 > 0.f) ? rsqrtf(d1) : 0.f;
        s_dis2[0][lane] = (d2 > 0.f) ? rsqrtf(d2) : 0.f;
    }
    if (w == 1 && lane < NN) {
        const float4* ar = (const float4*)&s_adj[lane*ADJ_S];
        const float4* mr = (const float4*)&s_m[1][0];
        float4 d2v = make_float4(0,0,0,0);
        #pragma unroll
        for (int j4 = 0; j4 < 16; ++j4) {
            float4 a = ar[j4], m4 = mr[j4];
            d2v.x += a.x*m4.x; d2v.y += a.y*m4.y; d2v.z += a.z*m4.z; d2v.w += a.w*m4.w;
        }
        float d2 = (d2v.x + d2v.y + d2v.z + d2v.w) * s_m[1][lane];
        s_dis2[1][lane] = (d2 > 0.f) ? rsqrtf(d2) : 0.f;
    }
    for (int i = t; i < NB*NF; i += NTHREADS) {
        int bb = (i >= NF) ? 1 : 0;
        int ii = i - bb*NF;
        int n = ii / FF, f = ii - n*FF;
        s_xs2[bb][n*XS_S + f] = s_xs1[bb][n*XS_S + f] * s_m[bb][n];
    }
    __syncthreads();

    // ---- Chebyshev recursion: 2 paths x 2 batches per dot pass ----
    const int n_id = t / FF, f_id = t - n_id*FF;   // valid when t < NF
    for (int k = 1; k < KC; ++k) {
        if (t < NF) {
            int xo = n_id*XS_S + (k-1)*FF + f_id;
            int uo = f_id*ADJ_S + n_id;
            float d1 = s_dis1[n_id];
            s_u1[0][uo] = d1 * s_xs1[0][xo];
            s_u1[1][uo] = d1 * s_xs1[1][xo];
            s_u2[0][uo] = s_dis2[0][n_id] * s_xs2[0][xo];
            s_u2[1][uo] = s_dis2[1][n_id] * s_xs2[1][xo];
        }
        __syncthreads();
        if (t < NF) {
            const float4* ar  = (const float4*)&s_adj[n_id*ADJ_S];
            const float4* u10 = (const float4*)&s_u1[0][f_id*ADJ_S];
            const float4* u11 = (const float4*)&s_u1[1][f_id*ADJ_S];
            const float4* u20 = (const float4*)&s_u2[0][f_id*ADJ_S];
            const float4* u21 = (const float4*)&s_u2[1][f_id*ADJ_S];
            float4 a10 = make_float4(0,0,0,0), a11 = make_float4(0,0,0,0);
            float4 a20 = make_float4(0,0,0,0), a21 = make_float4(0,0,0,0);
            #pragma unroll
            for (int j4 = 0; j4 < 16; ++j4) {
                float4 av = ar[j4];
                float4 v10 = u10[j4], v11 = u11[j4], v20 = u20[j4], v21 = u21[j4];
                a10.x += av.x*v10.x; a10.y += av.y*v10.y; a10.z += av.z*v10.z; a10.w += av.w*v10.w;
                a11.x += av.x*v11.x; a11.y += av.y*v11.y; a11.z += av.z*v11.z; a11.w += av.w*v11.w;
                a20.x += av.x*v20.x; a20.y += av.y*v20.y; a20.z += av.z*v20.z; a20.w += av.w*v20.w;
                a21.x += av.x*v21.x; a21.y += av.y*v21.y; a21.z += av.z*v21.z; a21.w += av.w*v21.w;
            }
            float s10 = a10.x+a10.y+a10.z+a10.w, s11 = a11.x+a11.y+a11.z+a11.w;
            float s20 = a20.x+a20.y+a20.z+a20.w, s21 = a21.x+a21.y+a21.z+a21.w;
            float c = (k == 1) ? 1.0f : 2.0f;
            float v10s = -c * s_dis1[n_id] * s10;
            float v11s = -c * s_dis1[n_id] * s11;
            float v20s = -c * s_dis2[0][n_id] * s20;
            float v21s = -c * s_dis2[1][n_id] * s21;
            int xo = n_id*XS_S + k*FF + f_id;
            if (k >= 2) {
                int xp = n_id*XS_S + (k-2)*FF + f_id;
                v10s -= s_xs1[0][xp]; v11s -= s_xs1[1][xp];
                v20s -= s_xs2[0][xp]; v21s -= s_xs2[1][xp];
            }
            s_xs1[0][xo] = v10s; s_xs1[1][xo] = v11s;
            s_xs2[0][xo] = v20s; s_xs2[1][xo] = v21s;
        }
        __syncthreads();
    }

    // ---- einsum + ReLU + FC, one head per pass, both batches fused ----
    const int o = lane;   // CO == 64

    auto head_pass = [&](const float* __restrict__ wsrc, const float* __restrict__ bsrc,
                         const float* __restrict__ fsrc, const float (*xs)[NN*XS_S],
                         int nouts, int slot) {
        float4 wr[5];
        #pragma unroll
        for (int c = 0; c < 5; ++c)
            wr[c] = make_float4(wsrc[(4*c+0)*CO + o], wsrc[(4*c+1)*CO + o],
                                wsrc[(4*c+2)*CO + o], wsrc[(4*c+3)*CO + o]);
        float bias = bsrc[o];
        float a0[2] = {0,0}, a1[2] = {0,0}, a2[2] = {0,0};
        for (int n = w; n < NN; n += 5) {
            const float4* xr0 = (const float4*)&xs[0][n*XS_S];
            const float4* xr1 = (const float4*)&xs[1][n*XS_S];
            float4 h0v = make_float4(0,0,0,0), h1v = make_float4(0,0,0,0);
            #pragma unroll
            for (int c = 0; c < 5; ++c) {
                float4 x0v = xr0[c], x1v = xr1[c];
                h0v.x += x0v.x*wr[c].x; h0v.y += x0v.y*wr[c].y;
                h0v.z += x0v.z*wr[c].z; h0v.w += x0v.w*wr[c].w;
                h1v.x += x1v.x*wr[c].x; h1v.y += x1v.y*wr[c].y;
                h1v.z += x1v.z*wr[c].z; h1v.w += x1v.w*wr[c].w;
            }
            float h0 = fmaxf(bias + h0v.x + h0v.y + h0v.z + h0v.w, 0.f);
            float h1 = fmaxf(bias + h1v.x + h1v.y + h1v.z + h1v.w, 0.f);
            const float* fp = fsrc + (n*CO + o)*nouts;
            float f0 = fp[0], f1 = fp[1];
            a0[0] += h0*f0; a1[0] += h0*f1;
            a0[1] += h1*f0; a1[1] += h1*f1;
            if (nouts == 3) {
                float f2 = fp[2];
                a2[0] += h0*f2; a2[1] += h1*f2;
            }
        }
        #pragma unroll
        for (int off = 32; off > 0; off >>= 1) {
            #pragma unroll
            for (int bb = 0; bb < 2; ++bb) {
                a0[bb] += __shfl_down(a0[bb], off);
                a1[bb] += __shfl_down(a1[bb], off);
                if (nouts == 3) a2[bb] += __shfl_down(a2[bb], off);
            }
        }
        if (o == 0) {
            #pragma unroll
            for (int bb = 0; bb < 2; ++bb) {
                s_red[w][bb*8 + slot+0] = a0[bb];
                s_red[w][bb*8 + slot+1] = a1[bb];
                if (nouts == 3) s_red[w][bb*8 + slot+2] = a2[bb];
            }
        }
    };

    head_pass(gc1_w, gc1_b, fc1_w, s_xs1, 3, 0);
    head_pass(gc2_w, gc2_b, fc2_w, s_xs2, 3, 3);
    head_pass(gc_w,  gc_b,  cls_w, s_xs1, 2, 6);
    __syncthreads();

    // ---- epilogue: waves 0/1 each finish one batch ----
    if (w < NB && lane == 0) {
        const int bb = w;
        float r[8];
        #pragma unroll
        for (int i = 0; i < 8; ++i) {
            float s = 0.f;
            for (int wv = 0; wv < 5; ++wv) s += s_red[wv][bb*8 + i];
            r[i] = s;
        }
        float l1c[3], l2c[3];
        #pragma unroll
        for (int c = 0; c < 3; ++c) { l1c[c] = r[c] + fc1_b[c]; l2c[c] = r[3+c] + fc2_b[c]; }
        float g0 = r[6] + cls_b[0], g1 = r[7] + cls_b[1];
        float mx = fmaxf(g0, g1);
        float e0 = expf(g0 - mx), e1 = expf(g1 - mx);
        float inv = 1.0f / (e0 + e1);
        float p0 = e0*inv, p1 = e1*inv;
        float* op = out + (b0 + bb)*3;
        op[0] = l1c[0]*p0 + l2c[0]*p1;
        op[1] = l1c[1]*p0 + l2c[1]*p1;
        op[2] = l1c[2]*p0 + l2c[2]*p1;
    }
}

extern "C" void kernel_launch(void* const* d_in, const int* in_sizes, int n_in,
                              void* d_out, int out_size, void* d_ws, size_t ws_size,
                              hipStream_t stream) {
    const float* x      = (const float*)d_in[0];
    const float* adj    = (const float*)d_in[1];
    const int*   midx   = (const int*)  d_in[2];
    const float* gc_w   = (const float*)d_in[3];
    const float* gc_b   = (const float*)d_in[4];
    const float* gc1_w  = (const float*)d_in[5];
    const float* gc1_b  = (const float*)d_in[6];
    const float* gc2_w  = (const float*)d_in[7];
    const float* gc2_b  = (const float*)d_in[8];
    const float* fc1_w  = (const float*)d_in[9];
    const float* fc1_b  = (const float*)d_in[10];
    const float* fc2_w  = (const float*)d_in[11];
    const float* fc2_b  = (const float*)d_in[12];
    const float* cls_w  = (const float*)d_in[13];
    const float* cls_b  = (const float*)d_in[14];
    float* o = (float*)d_out;
    hipLaunchKernelGGL(gnn_fused, dim3(BATCH/NB), dim3(NTHREADS), 0, stream,
        x, adj, midx, gc_w, gc_b, gc1_w, gc1_b, gc2_w, gc2_b,
        fc1_w, fc1_b, fc2_w, fc2_b, cls_w, cls_b, o);
}

// Round 5
// 57.215 us; speedup vs baseline: 2.6703x; 2.2589x over previous
//
#include <hip/hip_runtime.h>

#define NN 62
#define FF 5
#define KC 4
#define CO 64
#define NSEL 31
#define NF 310
#define NBATCH 4096
#define TPB 256        // 4 waves
#define BPB 8          // batches per block (4 waves x 2 each)
#define XS_ST 40       // xs row stride in bf16 elems (20 used, rest zero)
#define AD_ST 72       // adj row stride in bf16 elems
#define UT_BY 144      // U_t row (per col) stride bytes (72 j-elems)
#define XS_BY 80       // xs row stride bytes
#define AD_BY 144      // adj row stride bytes
#define WT_BY 80       // Wt row stride bytes (40 bf16)

typedef __bf16 bf16x8 __attribute__((ext_vector_type(8)));
typedef float f32x4 __attribute__((ext_vector_type(4)));

#define MFMA(A, B, C) __builtin_amdgcn_mfma_f32_16x16x32_bf16((A), (B), (C), 0, 0, 0)

__device__ __forceinline__ unsigned short f2bf(float f) {
    unsigned u = __float_as_uint(f);
    u += 0x7fffu + ((u >> 16) & 1u);
    return (unsigned short)(u >> 16);
}
__device__ __forceinline__ float bf2f(unsigned short s) {
    return __uint_as_float(((unsigned)s) << 16);
}
__device__ __forceinline__ bf16x8 ldfrag(const unsigned short* p, int byte_off) {
    return *(const bf16x8*)((const char*)p + byte_off);
}

__global__ __launch_bounds__(TPB) void gnn_mfma(
    const float* __restrict__ x, const float* __restrict__ adj,
    const int* __restrict__ mask_idx,
    const float* __restrict__ gc_w, const float* __restrict__ gc_b,
    const float* __restrict__ gc1_w, const float* __restrict__ gc1_b,
    const float* __restrict__ gc2_w, const float* __restrict__ gc2_b,
    const float* __restrict__ fc1_w, const float* __restrict__ fc1_b,
    const float* __restrict__ fc2_w, const float* __restrict__ fc2_b,
    const float* __restrict__ cls_w, const float* __restrict__ cls_b,
    float* __restrict__ out)
{
    __shared__ __align__(16) unsigned short s_adjb[64 * AD_ST];   // 9216 B, bf16, zero-padded
    __shared__ __align__(16) unsigned short s_wt[3 * 64 * 40];    // 15360 B, W^T [head][o][kf]
    __shared__ float s_bias[3][64];                               // 768 B
    __shared__ float s_dis1[64];                                  // 256 B
    __shared__ float s_dis2[BPB][64];                             // 2048 B
    __shared__ float s_msk[BPB][64];                              // 2048 B
    __shared__ __align__(16) unsigned short s_ut[4][16 * AD_ST];  // 9216 B, per-wave U^T [col][j]
    __shared__ __align__(16) unsigned short s_xs[4][2][64 * XS_ST]; // 40960 B, per-wave xs [path][n][kf]

    const int t = threadIdx.x;
    const int w = t >> 6, lane = t & 63;
    const int g = lane >> 4, c = lane & 15;
    const int b0 = blockIdx.x * BPB;

    // ================= block-cooperative staging =================
    for (int i = t; i < 64 * AD_ST; i += TPB) {
        int r = i / AD_ST, cc = i - r * AD_ST;
        float v = (r < NN && cc < NN) ? adj[r * NN + cc] : 0.0f;
        s_adjb[i] = f2bf(v);
    }
    for (int i = t; i < 3 * 64 * 40; i += TPB) {
        int head = i / 2560, rem = i - head * 2560;
        int o = rem / 40, kf = rem - o * 40;
        const float* wp = (head == 0) ? gc1_w : (head == 1) ? gc2_w : gc_w;
        s_wt[i] = f2bf((kf < KC * FF) ? wp[kf * CO + o] : 0.0f);
    }
    if (t < 192) {
        int head = t >> 6, o = t & 63;
        const float* bp = (head == 0) ? gc1_b : (head == 1) ? gc2_b : gc_b;
        s_bias[head][o] = bp[o];
    }
    for (int i = t; i < BPB * 64; i += TPB) ((float*)s_msk)[i] = 0.0f;
    __syncthreads();   // B1

    if (t < BPB * NSEL) {
        int bt = t / NSEL, s = t - bt * NSEL;
        s_msk[bt][mask_idx[(b0 + bt) * NSEL + s]] = 1.0f;  // same-value races benign
    }
    if (t < 64) {
        float d = 0.0f;
        for (int l = 0; l < NN; ++l) d += bf2f(s_adjb[t * AD_ST + l]);
        s_dis1[t] = (d > 0.0f) ? rsqrtf(d) : 0.0f;         // rows 62,63 -> 0
    }
    __syncthreads();   // B2

    for (int task = t; task < BPB * 64; task += TPB) {
        int bt = task >> 6, j = task & 63;
        float s = 0.0f;
        for (int l = 0; l < NN; ++l) s += bf2f(s_adjb[j * AD_ST + l]) * s_msk[bt][l];
        s *= s_msk[bt][j];
        s_dis2[bt][j] = (s > 0.0f) ? rsqrtf(s) : 0.0f;
    }
    __syncthreads();   // B3  -- last barrier; waves independent from here

    // ================= wave-private: 2 batches per wave =================
    {   // zero xs once per wave (covers pad cols 20..39 and rows 62,63 forever)
        unsigned* z = (unsigned*)&s_xs[w][0][0];
        for (int i = lane; i < 2560; i += 64) z[i] = 0u;
    }

    bf16x8 A1f[2][4], A2f[2][4];

    #pragma unroll
    for (int bi = 0; bi < 2; ++bi) {
        const int bb = w * 2 + bi;
        const int b  = b0 + bb;

        // ---- stage x0 (path1 = x, path2 = x*m) into xs k=0 slice ----
        const float* xb = x + (size_t)b * NF;
        for (int e = lane; e < NF; e += 64) {
            int n = e / 5, f = e - n * 5;
            float v = xb[e];
            s_xs[w][0][n * XS_ST + f] = f2bf(v);
            s_xs[w][1][n * XS_ST + f] = f2bf(v * s_msk[bb][n]);
        }

        // ---- per-lane dis selection (col<5: path1, col<10: path2, else 0) ----
        float dsel[16];
        const float* dsp = (c < 5) ? s_dis1 : s_dis2[bb];
        #pragma unroll
        for (int mt = 0; mt < 4; ++mt)
            #pragma unroll
            for (int i = 0; i < 4; ++i)
                dsel[mt * 4 + i] = (c < 10) ? dsp[mt * 16 + g * 4 + i] : 0.0f;

        // ---- x0 fragments (C-layout: row = mt*16+g*4+i, col = c) ----
        const int f_c = (c < 5) ? c : (c < 10 ? c - 5 : 0);
        const unsigned short* xsp = (c < 5) ? s_xs[w][0] : s_xs[w][1];
        f32x4 xA[4];   // x_{k-2} chain start = x0
        #pragma unroll
        for (int mt = 0; mt < 4; ++mt)
            #pragma unroll
            for (int i = 0; i < 4; ++i) {
                int r = mt * 16 + g * 4 + i;
                xA[mt][i] = (c < 10) ? bf2f(xsp[r * XS_ST + f_c]) : 0.0f;
            }

        // ---- U0 = dis .* x0  ->  U^T LDS [col][j] ----
        #pragma unroll
        for (int mt = 0; mt < 4; ++mt) {
            unsigned p01 = (unsigned)f2bf(dsel[mt*4+0] * xA[mt][0]) |
                           ((unsigned)f2bf(dsel[mt*4+1] * xA[mt][1]) << 16);
            unsigned p23 = (unsigned)f2bf(dsel[mt*4+2] * xA[mt][2]) |
                           ((unsigned)f2bf(dsel[mt*4+3] * xA[mt][3]) << 16);
            *(uint2*)((char*)s_ut[w] + c * UT_BY + mt * 32 + g * 8) = make_uint2(p01, p23);
        }

        // ---- adj A-fragments (row = mt*16+c, k = kf2*32+g*8+i) ----
        bf16x8 adjA[4][2];
        #pragma unroll
        for (int mt = 0; mt < 4; ++mt)
            #pragma unroll
            for (int kf2 = 0; kf2 < 2; ++kf2)
                adjA[mt][kf2] = ldfrag(s_adjb, (mt * 16 + c) * AD_BY + kf2 * 64 + g * 16);

        // ---- Chebyshev steps k=1..3 (wave-private, no barriers) ----
        f32x4 x1f[4], x2f[4];
        #pragma unroll
        for (int k = 1; k <= 3; ++k) {
            const float cc_k = (k == 1) ? 1.0f : 2.0f;
            bf16x8 Uf0 = ldfrag(s_ut[w], c * UT_BY + 0 + g * 16);
            bf16x8 Uf1 = ldfrag(s_ut[w], c * UT_BY + 64 + g * 16);
            #pragma unroll
            for (int mt = 0; mt < 4; ++mt) {
                f32x4 Cv = {0.f, 0.f, 0.f, 0.f};
                Cv = MFMA(adjA[mt][0], Uf0, Cv);
                Cv = MFMA(adjA[mt][1], Uf1, Cv);
                f32x4 xn;
                #pragma unroll
                for (int i = 0; i < 4; ++i) {
                    float v = -cc_k * dsel[mt * 4 + i] * Cv[i];
                    if (k == 2) v -= xA[mt][i];
                    if (k == 3) v -= x1f[mt][i];
                    xn[i] = v;
                }
                if (c < 10) {   // write xs slice k (path from col)
                    unsigned short* dst = (c < 5) ? s_xs[w][0] : s_xs[w][1];
                    #pragma unroll
                    for (int i = 0; i < 4; ++i) {
                        int r = mt * 16 + g * 4 + i;
                        dst[r * XS_ST + k * 5 + f_c] = f2bf(xn[i]);
                    }
                }
                if (k < 3) {    // write U_k for next step
                    unsigned p01 = (unsigned)f2bf(dsel[mt*4+0] * xn[0]) |
                                   ((unsigned)f2bf(dsel[mt*4+1] * xn[1]) << 16);
                    unsigned p23 = (unsigned)f2bf(dsel[mt*4+2] * xn[2]) |
                                   ((unsigned)f2bf(dsel[mt*4+3] * xn[3]) << 16);
                    *(uint2*)((char*)s_ut[w] + c * UT_BY + mt * 32 + g * 8) = make_uint2(p01, p23);
                }
                if (k == 1) x1f[mt] = xn;
                if (k == 2) x2f[mt] = xn;
                (void)x2f;
            }
        }

        // ---- einsum A-frags for this batch (row n = mt*16+c, k = kf) ----
        #pragma unroll
        for (int mt = 0; mt < 4; ++mt) {
            A1f[bi][mt] = ldfrag(s_xs[w][0], (mt * 16 + c) * XS_BY + g * 16);
            A2f[bi][mt] = ldfrag(s_xs[w][1], (mt * 16 + c) * XS_BY + g * 16);
        }
    } // bi

    // ================= fused einsum + ReLU + FC for the batch pair =================
    float acc[2][8];
    #pragma unroll
    for (int bi = 0; bi < 2; ++bi)
        #pragma unroll
        for (int q = 0; q < 8; ++q) acc[bi][q] = 0.0f;

    float b1v[4], b2v[4], bgv[4];
    #pragma unroll
    for (int nt = 0; nt < 4; ++nt) {
        b1v[nt] = s_bias[0][nt * 16 + c];
        b2v[nt] = s_bias[1][nt * 16 + c];
        bgv[nt] = s_bias[2][nt * 16 + c];
    }

    #pragma unroll
    for (int mt = 0; mt < 4; ++mt) {
        #pragma unroll
        for (int nt = 0; nt < 4; ++nt) {
            bf16x8 W1f = ldfrag(s_wt, (0 * 64 + nt * 16 + c) * WT_BY + g * 16);
            bf16x8 W2f = ldfrag(s_wt, (1 * 64 + nt * 16 + c) * WT_BY + g * 16);
            bf16x8 Wgf = ldfrag(s_wt, (2 * 64 + nt * 16 + c) * WT_BY + g * 16);
            const f32x4 z = {0.f, 0.f, 0.f, 0.f};
            f32x4 C1a = MFMA(A1f[0][mt], W1f, z);
            f32x4 C1b = MFMA(A1f[1][mt], W1f, z);
            f32x4 Cga = MFMA(A1f[0][mt], Wgf, z);
            f32x4 Cgb = MFMA(A1f[1][mt], Wgf, z);
            f32x4 C2a = MFMA(A2f[0][mt], W2f, z);
            f32x4 C2b = MFMA(A2f[1][mt], W2f, z);
            #pragma unroll
            for (int i = 0; i < 4; ++i) {
                int r = mt * 16 + g * 4 + i;
                if (r < NN) {
                    int base = r * CO + nt * 16 + c;
                    const float* f1p = fc1_w + base * 3;
                    const float* f2p = fc2_w + base * 3;
                    const float* fgp = cls_w + base * 2;
                    float f10 = f1p[0], f11 = f1p[1], f12 = f1p[2];
                    float f20 = f2p[0], f21 = f2p[1], f22 = f2p[2];
                    float fg0 = fgp[0], fg1 = fgp[1];
                    float h1a = fmaxf(C1a[i] + b1v[nt], 0.f);
                    float h1b = fmaxf(C1b[i] + b1v[nt], 0.f);
                    float h2a = fmaxf(C2a[i] + b2v[nt], 0.f);
                    float h2b = fmaxf(C2b[i] + b2v[nt], 0.f);
                    float hga = fmaxf(Cga[i] + bgv[nt], 0.f);
                    float hgb = fmaxf(Cgb[i] + bgv[nt], 0.f);
                    acc[0][0] += h1a * f10; acc[0][1] += h1a * f11; acc[0][2] += h1a * f12;
                    acc[0][3] += h2a * f20; acc[0][4] += h2a * f21; acc[0][5] += h2a * f22;
                    acc[0][6] += hga * fg0; acc[0][7] += hga * fg1;
                    acc[1][0] += h1b * f10; acc[1][1] += h1b * f11; acc[1][2] += h1b * f12;
                    acc[1][3] += h2b * f20; acc[1][4] += h2b * f21; acc[1][5] += h2b * f22;
                    acc[1][6] += hgb * fg0; acc[1][7] += hgb * fg1;
                }
            }
        }
    }

    // ---- wave reduction ----
    #pragma unroll
    for (int off = 32; off > 0; off >>= 1)
        #pragma unroll
        for (int bi = 0; bi < 2; ++bi)
            #pragma unroll
            for (int q = 0; q < 8; ++q)
                acc[bi][q] += __shfl_down(acc[bi][q], off);

    if (lane == 0) {
        #pragma unroll
        for (int bi = 0; bi < 2; ++bi) {
            const int b = b0 + w * 2 + bi;
            float l0 = acc[bi][0] + fc1_b[0];
            float l1 = acc[bi][1] + fc1_b[1];
            float l2 = acc[bi][2] + fc1_b[2];
            float m0 = acc[bi][3] + fc2_b[0];
            float m1 = acc[bi][4] + fc2_b[1];
            float m2 = acc[bi][5] + fc2_b[2];
            float g0 = acc[bi][6] + cls_b[0];
            float g1 = acc[bi][7] + cls_b[1];
            float mx = fmaxf(g0, g1);
            float e0 = expf(g0 - mx), e1 = expf(g1 - mx);
            float inv = 1.0f / (e0 + e1);
            float p0 = e0 * inv, p1 = e1 * inv;
            out[b * 3 + 0] = l0 * p0 + m0 * p1;
            out[b * 3 + 1] = l1 * p0 + m1 * p1;
            out[b * 3 + 2] = l2 * p0 + m2 * p1;
        }
    }
}

extern "C" void kernel_launch(void* const* d_in, const int* in_sizes, int n_in,
                              void* d_out, int out_size, void* d_ws, size_t ws_size,
                              hipStream_t stream) {
    const float* x      = (const float*)d_in[0];
    const float* adj    = (const float*)d_in[1];
    const int*   midx   = (const int*)  d_in[2];
    const float* gc_w   = (const float*)d_in[3];
    const float* gc_b   = (const float*)d_in[4];
    const float* gc1_w  = (const float*)d_in[5];
    const float* gc1_b  = (const float*)d_in[6];
    const float* gc2_w  = (const float*)d_in[7];
    const float* gc2_b  = (const float*)d_in[8];
    const float* fc1_w  = (const float*)d_in[9];
    const float* fc1_b  = (const float*)d_in[10];
    const float* fc2_w  = (const float*)d_in[11];
    const float* fc2_b  = (const float*)d_in[12];
    const float* cls_w  = (const float*)d_in[13];
    const float* cls_b  = (const float*)d_in[14];
    float* o = (float*)d_out;
    hipLaunchKernelGGL(gnn_mfma, dim3(NBATCH / BPB), dim3(TPB), 0, stream,
        x, adj, midx, gc_w, gc_b, gc1_w, gc1_b, gc2_w, gc2_b,
        fc1_w, fc1_b, fc2_w, fc2_b, cls_w, cls_b, o);
}